// Round 7
// baseline (449.183 us; speedup 1.0000x reference)
//
#include <hip/hip_runtime.h>

#define NMAT 2048
#define KATTR 64
#define CAP 64
#define TCAP 192  // merged 4-row edge list cap (mean 66, +15 sigma safe)
#define NITER 10
#define SENT_A 2048  // Phase A sentinel: extra zeroed row of M buffers
#define SENT_B 2057  // Phase B sentinel: swz(2057)=8232, outside real swz image

typedef unsigned short ushort4v __attribute__((ext_vector_type(4)));

__device__ __forceinline__ unsigned short f2bf(float f) {
  unsigned u = __float_as_uint(f);
  return (unsigned short)((u + 0x7fff + ((u >> 16) & 1)) >> 16);
}
__device__ __forceinline__ float bf2f(unsigned short b) {
  return __uint_as_float((unsigned)b << 16);
}
__device__ __forceinline__ float bflo(unsigned v) {
  return __uint_as_float(v << 16);
}
__device__ __forceinline__ float bfhi(unsigned v) {
  return __uint_as_float(v & 0xffff0000u);
}
// swizzled LDS dword index (proven v3/v5/v7)
__device__ __forceinline__ int swz(int c) { return 4 * c + (((c >> 3) & 7) << 2); }

// --------------------------------------------------------------------------
// Build padded adjacency (ELL); sentinel-fill unused slots up to CAP.
// idxT4 (Phase B): 4 edges/group at idxT4[g*NMAT*4 + r*4 + (p&3)].
// --------------------------------------------------------------------------
__global__ __launch_bounds__(256) void k_build(
    const float* __restrict__ A, unsigned short* __restrict__ idx,
    unsigned short* __restrict__ idxT4, int* __restrict__ cnt) {
  __shared__ int lcnt;
  int r = blockIdx.x;
  if (threadIdx.x == 0) lcnt = 0;
  __syncthreads();
  const float* row = A + (size_t)r * NMAT;
  for (int c = threadIdx.x; c < NMAT; c += 256) {
    if (row[c] != 0.0f) {
      int p = atomicAdd(&lcnt, 1);
      if (p < CAP) {
        idx[r * CAP + p] = (unsigned short)c;
        if (idxT4)
          idxT4[(size_t)(p >> 2) * (NMAT * 4) + r * 4 + (p & 3)] =
              (unsigned short)c;
      }
    }
  }
  __syncthreads();
  int n = lcnt < CAP ? lcnt : CAP;
  for (int p = n + threadIdx.x; p < CAP; p += 256) {
    idx[r * CAP + p] = (unsigned short)SENT_A;
    if (idxT4)
      idxT4[(size_t)(p >> 2) * (NMAT * 4) + r * 4 + (p & 3)] =
          (unsigned short)SENT_B;
  }
  if (threadIdx.x == 0) cnt[r] = n;
}

// --------------------------------------------------------------------------
// Merged 4-row edge list for Phase A, globally k-sorted (deterministic).
// Entry = k | (row<<14), rows = local 0..3. All blocks sweep k ascending ->
// co-resident blocks on an XCD hit the same M rows in the same order (L2
// dedup of the deg-fold re-reads). Two-pass: count, scan, write.
// --------------------------------------------------------------------------
__global__ __launch_bounds__(256) void k_build4(const float* __restrict__ A,
                                                unsigned short* __restrict__ mlist,
                                                int* __restrict__ mcnt) {
  __shared__ int wsum[4];
  __shared__ int stot;
  int b = blockIdx.x;  // tile = rows 4b..4b+3
  int t = threadIdx.x;
  int i0 = b * 4;
  // pass 1: count entries for k in [t*8, t*8+8)
  int ln = 0;
  for (int u = 0; u < 8; ++u) {
    int k = t * 8 + u;
    for (int r = 0; r < 4; ++r)
      if (A[(size_t)(i0 + r) * NMAT + k] != 0.0f) ++ln;
  }
  // inclusive scan over 256 threads
  int lane = t & 63, wv = t >> 6;
  int v = ln;
  for (int o = 1; o < 64; o <<= 1) {
    int x = __shfl_up(v, o);
    if (lane >= o) v += x;
  }
  if (lane == 63) wsum[wv] = v;
  __syncthreads();
  if (t == 0) {
    int s = 0;
    for (int w = 0; w < 4; ++w) {
      int x = wsum[w];
      wsum[w] = s;
      s += x;
    }
    stot = s;
  }
  __syncthreads();
  int off = v - ln + wsum[wv];  // exclusive offset
  // pass 2: write entries in (k, r) order
  unsigned short* mp = mlist + (size_t)b * TCAP;
  for (int u = 0; u < 8; ++u) {
    int k = t * 8 + u;
    for (int r = 0; r < 4; ++r)
      if (A[(size_t)(i0 + r) * NMAT + k] != 0.0f)
        mp[off++] = (unsigned short)(k | (r << 14));
  }
  int tot = stot;
  for (int p = tot + t; p < TCAP; p += 256)
    mp[p] = (unsigned short)SENT_A;  // k=2048 (zeroed row), r=0
  if (t == 0) mcnt[b] = (tot + 7) & ~7;
}

__global__ __launch_bounds__(256) void k_norm(const float* __restrict__ Nin,
                                              float* __restrict__ Nout) {
  int row = blockIdx.x * 4 + (threadIdx.x >> 6);
  int lane = threadIdx.x & 63;
  float v = Nin[(size_t)row * KATTR + lane];
  float ss = v * v;
#pragma unroll
  for (int o = 32; o > 0; o >>= 1) ss += __shfl_xor(ss, o);
  float nrm = sqrtf(ss);
  Nout[(size_t)row * KATTR + lane] = (nrm > 0.f) ? v / nrm : 0.f;
}

__global__ void k_gatherN(const unsigned short* __restrict__ idx,
                          const int* __restrict__ cnt,
                          const float* __restrict__ Nn,
                          float* __restrict__ C) {
  int i = blockIdx.x;
  int lane = threadIdx.x;  // blockDim = 64
  int nn = cnt[i];
  const unsigned short* ip = idx + i * CAP;
  float acc = 0.f;
  for (int t = 0; t < nn; ++t) {
    int k = ip[t];
    acc += Nn[(size_t)k * KATTR + lane];
  }
  C[(size_t)i * KATTR + lane] = acc;
}

__global__ __launch_bounds__(256) void k_transpose(const float* __restrict__ H,
                                                   float* __restrict__ Ht) {
  __shared__ float tile[64][65];
  int j0 = blockIdx.x * 64;
  int i0 = blockIdx.y * 64;
  int c = threadIdx.x & 63;
  int r0 = threadIdx.x >> 6;
  for (int r = r0; r < 64; r += 4)
    tile[r][c] = H[(size_t)(j0 + r) * NMAT + i0 + c];
  __syncthreads();
  for (int r = r0; r < 64; r += 4)
    Ht[(size_t)(i0 + r) * NMAT + j0 + c] = tile[c][r];
}

// Zero the sentinel row (row 2048) of the gather buffers, once.
__global__ __launch_bounds__(1024) void k_zrow(unsigned short* __restrict__ Mb0,
                                               unsigned short* __restrict__ Mb1) {
  size_t Z = (size_t)NMAT * NMAT;
  for (int o = threadIdx.x; o < NMAT; o += 1024) {
    Mb0[Z + o] = 0;
    Mb1[Z + o] = 0;
  }
}

// --------------------------------------------------------------------------
// q = Nm>0&dm>0 ? Nm*rsqrt(Nm*dm) : 0.
// QM = pack(bf16(alpha*q^2) | bf16((1-a)*q*Ht) << 16)  (iters 0..8)
// QL = pack(bf16(alpha*q)   | bf16((1-a)*Ht)   << 16)  (last iter)
// --------------------------------------------------------------------------
__global__ __launch_bounds__(256) void k_q(
    const float* __restrict__ N1n, const float* __restrict__ C1,
    const float* __restrict__ N2n, const float* __restrict__ C2,
    const float* __restrict__ Ht, unsigned* __restrict__ QM,
    unsigned* __restrict__ QL, unsigned short* __restrict__ M) {
  __shared__ float sA[64][68];
  __shared__ float sB[64][68];
  int i0 = blockIdx.y * 64, j0 = blockIdx.x * 64;
  int c = threadIdx.x & 63, r0 = threadIdx.x >> 6;
  int tx = threadIdx.x & 15, ty = threadIdx.x >> 4;
  const float alpha = 0.82f;

  float nmv[4][4] = {};
  float dmv[4][4] = {};

  for (int r = r0; r < 64; r += 4) {
    sA[c][r] = N1n[(size_t)(i0 + r) * KATTR + c];
    sB[c][r] = N2n[(size_t)(j0 + r) * KATTR + c];
  }
  __syncthreads();
#pragma unroll 4
  for (int k = 0; k < 64; ++k) {
    float4 a = *(const float4*)&sA[k][ty * 4];
    float4 b = *(const float4*)&sB[k][tx * 4];
    float av[4] = {a.x, a.y, a.z, a.w};
    float bv[4] = {b.x, b.y, b.z, b.w};
#pragma unroll
    for (int ii = 0; ii < 4; ++ii)
#pragma unroll
      for (int jj = 0; jj < 4; ++jj)
        nmv[ii][jj] = fmaf(av[ii], bv[jj], nmv[ii][jj]);
  }
  __syncthreads();
  for (int r = r0; r < 64; r += 4) {
    sA[c][r] = C1[(size_t)(i0 + r) * KATTR + c];
    sB[c][r] = C2[(size_t)(j0 + r) * KATTR + c];
  }
  __syncthreads();
#pragma unroll 4
  for (int k = 0; k < 64; ++k) {
    float4 a = *(const float4*)&sA[k][ty * 4];
    float4 b = *(const float4*)&sB[k][tx * 4];
    float av[4] = {a.x, a.y, a.z, a.w};
    float bv[4] = {b.x, b.y, b.z, b.w};
#pragma unroll
    for (int ii = 0; ii < 4; ++ii)
#pragma unroll
      for (int jj = 0; jj < 4; ++jj)
        dmv[ii][jj] = fmaf(av[ii], bv[jj], dmv[ii][jj]);
  }

#pragma unroll
  for (int ii = 0; ii < 4; ++ii) {
    int i = i0 + ty * 4 + ii;
    size_t base = (size_t)i * NMAT + j0 + tx * 4;
    float4 hv = *(const float4*)&Ht[base];
    float hvv[4] = {hv.x, hv.y, hv.z, hv.w};
    unsigned qmv[4], qlv[4];
    ushort4v mv;
#pragma unroll
    for (int jj = 0; jj < 4; ++jj) {
      float nmx = nmv[ii][jj];
      float D = nmx * dmv[ii][jj];
      float qq = (D > 0.f) ? nmx * rsqrtf(D) : 0.f;
      float m0 = qq * hvv[jj];
      mv[jj] = f2bf(m0);
      qmv[jj] = (unsigned)f2bf(alpha * qq * qq) |
                ((unsigned)f2bf((1.0f - alpha) * m0) << 16);
      qlv[jj] = (unsigned)f2bf(alpha * qq) |
                ((unsigned)f2bf((1.0f - alpha) * hvv[jj]) << 16);
    }
    *(uint4*)&QM[base] = make_uint4(qmv[0], qmv[1], qmv[2], qmv[3]);
    *(uint4*)&QL[base] = make_uint4(qlv[0], qlv[1], qlv[2], qlv[3]);
    *(ushort4v*)&M[base] = mv;
  }
}

// accumulate one bf16-pair into the (wave-uniform) row's accumulators
#define ACC(w, rr)                  \
  {                                 \
    float lo = bflo(w);             \
    float hi = bfhi(w);             \
    if ((rr) == 0) {                \
      a00 += lo; a01 += hi;         \
    } else if ((rr) == 1) {         \
      a10 += lo; a11 += hi;         \
    } else if ((rr) == 2) {         \
      a20 += lo; a21 += hi;         \
    } else {                        \
      a30 += lo; a31 += hi;         \
    }                               \
  }

// --------------------------------------------------------------------------
// One full iteration, fused (v8 = v7 + k-sorted merged Phase A sweep).
// Grid 512 x 1024 (16 waves/block, 2 blocks/CU = 32 waves/CU).
// Phase A: single merged sweep over the tile's edges in ascending k order
//   (entry = k | row<<14, wave-uniform -> scalar index loads + uniform
//   branches). All blocks sweep k in the same order -> XCD-L2 dedups the
//   deg-fold M re-reads (predicted FETCH 120 -> ~80 MB).
// Phase B: v7-verbatim (b128 swizzled LDS gathers + packed-word epilogue).
// --------------------------------------------------------------------------
__global__ __launch_bounds__(1024, 8) void k_iter(
    const unsigned short* __restrict__ mlist, const int* __restrict__ mcnt,
    const unsigned short* __restrict__ idx2T4, const int* __restrict__ cnt2,
    const unsigned short* __restrict__ Min, const unsigned* __restrict__ QMx,
    unsigned short* __restrict__ Mout, float* __restrict__ sout, int last) {
  __shared__ float lds[4 * NMAT + 64];
  const int GS = NMAT * 4;  // idx2T4 group stride (ushorts)
  int i0 = blockIdx.x * 4;
  int tid = threadIdx.x;  // 0..1023
  int c0 = tid * 2;       // this thread's 2 columns

  if (tid == 0) *(float4*)&lds[swz(SENT_B)] = make_float4(0.f, 0.f, 0.f, 0.f);

  // ---- Phase A: merged k-sorted gather sweep ----
  int mn = mcnt[blockIdx.x];  // multiple of 8
  const unsigned short* mp = mlist + (size_t)blockIdx.x * TCAP;
  const unsigned short* Bb = Min + c0;
  float a00 = 0.f, a01 = 0.f, a10 = 0.f, a11 = 0.f;
  float a20 = 0.f, a21 = 0.f, a30 = 0.f, a31 = 0.f;
  for (int t = 0; t < mn; t += 8) {
    uint4 pk = *(const uint4*)(mp + t);
    int e0 = pk.x & 0xffff, e1 = pk.x >> 16;
    int e2 = pk.y & 0xffff, e3 = pk.y >> 16;
    int e4 = pk.z & 0xffff, e5 = pk.z >> 16;
    int e6 = pk.w & 0xffff, e7 = pk.w >> 16;
    unsigned w0 = *(const unsigned*)(Bb + (size_t)(e0 & 0x3fff) * NMAT);
    unsigned w1 = *(const unsigned*)(Bb + (size_t)(e1 & 0x3fff) * NMAT);
    unsigned w2 = *(const unsigned*)(Bb + (size_t)(e2 & 0x3fff) * NMAT);
    unsigned w3 = *(const unsigned*)(Bb + (size_t)(e3 & 0x3fff) * NMAT);
    unsigned w4 = *(const unsigned*)(Bb + (size_t)(e4 & 0x3fff) * NMAT);
    unsigned w5 = *(const unsigned*)(Bb + (size_t)(e5 & 0x3fff) * NMAT);
    unsigned w6 = *(const unsigned*)(Bb + (size_t)(e6 & 0x3fff) * NMAT);
    unsigned w7 = *(const unsigned*)(Bb + (size_t)(e7 & 0x3fff) * NMAT);
    ACC(w0, e0 >> 14);
    ACC(w1, e1 >> 14);
    ACC(w2, e2 >> 14);
    ACC(w3, e3 >> 14);
    ACC(w4, e4 >> 14);
    ACC(w5, e5 >> 14);
    ACC(w6, e6 >> 14);
    ACC(w7, e7 >> 14);
  }
  *(float4*)&lds[swz(c0)] = make_float4(a00, a10, a20, a30);
  *(float4*)&lds[swz(c0 + 1)] = make_float4(a01, a11, a21, a31);
  __syncthreads();

  // ---- Phase B: column gathers from LDS + epilogue (v7-verbatim) ----
#pragma unroll
  for (int jj = 0; jj < 2; ++jj) {
    int j = jj * 1024 + tid;
    int nn = cnt2[j];
    const unsigned short* bp = idx2T4 + j * 4;
    size_t off0 = (size_t)i0 * NMAT + j;
    unsigned wq0 = QMx[off0];
    unsigned wq1 = QMx[off0 + NMAT];
    unsigned wq2 = QMx[off0 + 2 * NMAT];
    unsigned wq3 = QMx[off0 + 3 * NMAT];
    uint2 g0 = *(const uint2*)(bp);
    uint2 g1 = *(const uint2*)(bp + GS);
    uint2 g2 = *(const uint2*)(bp + 2 * GS);
    uint2 g3 = *(const uint2*)(bp + 3 * GS);
    float s0 = 0.f, s1 = 0.f, s2 = 0.f, s3 = 0.f;
    float u0 = 0.f, u1 = 0.f, u2 = 0.f, u3 = 0.f;
    {
      float4 va = *(const float4*)&lds[swz(g0.x & 0xffff)];
      float4 vb = *(const float4*)&lds[swz(g0.x >> 16)];
      float4 vc = *(const float4*)&lds[swz(g0.y & 0xffff)];
      float4 vd = *(const float4*)&lds[swz(g0.y >> 16)];
      float4 ve = *(const float4*)&lds[swz(g1.x & 0xffff)];
      float4 vf = *(const float4*)&lds[swz(g1.x >> 16)];
      float4 vg = *(const float4*)&lds[swz(g1.y & 0xffff)];
      float4 vh = *(const float4*)&lds[swz(g1.y >> 16)];
      s0 += (va.x + vb.x) + (vc.x + vd.x);
      s1 += (va.y + vb.y) + (vc.y + vd.y);
      s2 += (va.z + vb.z) + (vc.z + vd.z);
      s3 += (va.w + vb.w) + (vc.w + vd.w);
      u0 += (ve.x + vf.x) + (vg.x + vh.x);
      u1 += (ve.y + vf.y) + (vg.y + vh.y);
      u2 += (ve.z + vf.z) + (vg.z + vh.z);
      u3 += (ve.w + vf.w) + (vg.w + vh.w);
    }
    {
      float4 va = *(const float4*)&lds[swz(g2.x & 0xffff)];
      float4 vb = *(const float4*)&lds[swz(g2.x >> 16)];
      float4 vc = *(const float4*)&lds[swz(g2.y & 0xffff)];
      float4 vd = *(const float4*)&lds[swz(g2.y >> 16)];
      float4 ve = *(const float4*)&lds[swz(g3.x & 0xffff)];
      float4 vf = *(const float4*)&lds[swz(g3.x >> 16)];
      float4 vg = *(const float4*)&lds[swz(g3.y & 0xffff)];
      float4 vh = *(const float4*)&lds[swz(g3.y >> 16)];
      s0 += (va.x + vb.x) + (vc.x + vd.x);
      s1 += (va.y + vb.y) + (vc.y + vd.y);
      s2 += (va.z + vb.z) + (vc.z + vd.z);
      s3 += (va.w + vb.w) + (vc.w + vd.w);
      u0 += (ve.x + vf.x) + (vg.x + vh.x);
      u1 += (ve.y + vf.y) + (vg.y + vh.y);
      u2 += (ve.z + vf.z) + (vg.z + vh.z);
      u3 += (ve.w + vf.w) + (vg.w + vh.w);
    }
    for (int t = 16; t < nn; t += 8) {
      uint2 ga = *(const uint2*)(bp + (size_t)(t >> 2) * GS);
      uint2 gb = *(const uint2*)(bp + (size_t)((t >> 2) + 1) * GS);
      float4 va = *(const float4*)&lds[swz(ga.x & 0xffff)];
      float4 vb = *(const float4*)&lds[swz(ga.x >> 16)];
      float4 vc = *(const float4*)&lds[swz(ga.y & 0xffff)];
      float4 vd = *(const float4*)&lds[swz(ga.y >> 16)];
      float4 ve = *(const float4*)&lds[swz(gb.x & 0xffff)];
      float4 vf = *(const float4*)&lds[swz(gb.x >> 16)];
      float4 vg = *(const float4*)&lds[swz(gb.y & 0xffff)];
      float4 vh = *(const float4*)&lds[swz(gb.y >> 16)];
      s0 += (va.x + vb.x) + (vc.x + vd.x);
      s1 += (va.y + vb.y) + (vc.y + vd.y);
      s2 += (va.z + vb.z) + (vc.z + vd.z);
      s3 += (va.w + vb.w) + (vc.w + vd.w);
      u0 += (ve.x + vf.x) + (vg.x + vh.x);
      u1 += (ve.y + vf.y) + (vg.y + vh.y);
      u2 += (ve.z + vf.z) + (vg.z + vh.z);
      u3 += (ve.w + vf.w) + (vg.w + vh.w);
    }
    float sa[4] = {s0 + u0, s1 + u1, s2 + u2, s3 + u3};
    if (last) {
      sout[off0] = fmaf(bflo(wq0), sa[0], bfhi(wq0));
      sout[off0 + NMAT] = fmaf(bflo(wq1), sa[1], bfhi(wq1));
      sout[off0 + 2 * NMAT] = fmaf(bflo(wq2), sa[2], bfhi(wq2));
      sout[off0 + 3 * NMAT] = fmaf(bflo(wq3), sa[3], bfhi(wq3));
    } else {
      Mout[off0] = f2bf(fmaf(bflo(wq0), sa[0], bfhi(wq0)));
      Mout[off0 + NMAT] = f2bf(fmaf(bflo(wq1), sa[1], bfhi(wq1)));
      Mout[off0 + 2 * NMAT] = f2bf(fmaf(bflo(wq2), sa[2], bfhi(wq2)));
      Mout[off0 + 3 * NMAT] = f2bf(fmaf(bflo(wq3), sa[3], bfhi(wq3)));
    }
  }
}

extern "C" void kernel_launch(void* const* d_in, const int* in_sizes, int n_in,
                              void* d_out, int out_size, void* d_ws,
                              size_t ws_size, hipStream_t stream) {
  const float* A1 = (const float*)d_in[0];
  const float* A2 = (const float*)d_in[1];
  const float* N1 = (const float*)d_in[2];
  const float* N2 = (const float*)d_in[3];
  const float* H = (const float*)d_in[4];
  float* s_out = (float*)d_out;

  char* p = (char*)d_ws;
  auto take = [&](size_t bytes) {
    char* r = p;
    p += (bytes + 255) & ~(size_t)255;
    return r;
  };
  unsigned short* idx1 = (unsigned short*)take((size_t)NMAT * CAP * 2);
  unsigned short* idx2 = (unsigned short*)take((size_t)NMAT * CAP * 2);
  unsigned short* idx2T4 = (unsigned short*)take((size_t)CAP * NMAT * 2);
  unsigned short* mlist = (unsigned short*)take((size_t)(NMAT / 4) * TCAP * 2);
  int* mcnt = (int*)take((size_t)(NMAT / 4) * 4);
  int* cnt1 = (int*)take((size_t)NMAT * 4);
  int* cnt2 = (int*)take((size_t)NMAT * 4);
  float* N1n = (float*)take((size_t)NMAT * KATTR * 4);
  float* N2n = (float*)take((size_t)NMAT * KATTR * 4);
  float* C1 = (float*)take((size_t)NMAT * KATTR * 4);
  float* C2 = (float*)take((size_t)NMAT * KATTR * 4);
  float* Ht = (float*)take((size_t)NMAT * NMAT * 4);
  unsigned* QM = (unsigned*)take((size_t)NMAT * NMAT * 4);
  unsigned* QL = (unsigned*)take((size_t)NMAT * NMAT * 4);
  unsigned short* Mb0 = (unsigned short*)take((size_t)(NMAT + 1) * NMAT * 2);
  unsigned short* Mb1 = (unsigned short*)take((size_t)(NMAT + 1) * NMAT * 2);
  if ((size_t)(p - (char*)d_ws) > ws_size) return;

  k_build<<<NMAT, 256, 0, stream>>>(A1, idx1, (unsigned short*)nullptr, cnt1);
  k_build<<<NMAT, 256, 0, stream>>>(A2, idx2, idx2T4, cnt2);
  k_build4<<<NMAT / 4, 256, 0, stream>>>(A1, mlist, mcnt);
  k_norm<<<NMAT / 4, 256, 0, stream>>>(N1, N1n);
  k_norm<<<NMAT / 4, 256, 0, stream>>>(N2, N2n);
  k_gatherN<<<NMAT, 64, 0, stream>>>(idx1, cnt1, N1n, C1);
  k_gatherN<<<NMAT, 64, 0, stream>>>(idx2, cnt2, N2n, C2);
  k_transpose<<<dim3(32, 32), 256, 0, stream>>>(H, Ht);
  k_q<<<dim3(32, 32), 256, 0, stream>>>(N1n, C1, N2n, C2, Ht, QM, QL, Mb0);
  k_zrow<<<1, 1024, 0, stream>>>(Mb0, Mb1);
  for (int it = 0; it < NITER; ++it) {
    const unsigned short* Min = (it & 1) ? Mb1 : Mb0;
    unsigned short* Mout = (it & 1) ? Mb0 : Mb1;
    int last = (it == NITER - 1) ? 1 : 0;
    const unsigned* QMx = last ? QL : QM;
    k_iter<<<NMAT / 4, 1024, 0, stream>>>(mlist, mcnt, idx2T4, cnt2, Min, QMx,
                                          Mout, s_out, last);
  }
}